// Round 10
// baseline (195.793 us; speedup 1.0000x reference)
//
#include <hip/hip_runtime.h>

// ManifoldAttentionLayer on MI355X — round 9
// R8 post-mortem: flash is LDS-read-bandwidth bound. Every wave reads the
// full 24KB K/V tile per iter; R8's 16 waves/CU x 24KB x 16 iters = 6.1MB
// LDS reads/CU -> ~30us floor at 85B/cyc (m134) — matches the flat 42us.
// Doubling waves (R7->R8) couldn't help; amortization = q-rows/wave.
// R9: 32 q/wave (K-frags reused across 2 n-tiles) x 8-wave blocks:
// 512 thr, 256 q/block, grid (16,4,4) = 1 block/CU. Halves LDS-read volume
// AND per-CU DMA AND K re-staging per head.

using short8  = __attribute__((ext_vector_type(8))) short;
using short4v = __attribute__((ext_vector_type(4))) short;
using float4v = __attribute__((ext_vector_type(4))) float;

#define MFMA16(a, b, c) __builtin_amdgcn_mfma_f32_16x16x32_bf16((a), (b), (c), 0, 0, 0)

#define LOG2E 1.44269504088896f

static __device__ __forceinline__ short f2bf(float f) {
    union { float f; unsigned u; } v; v.f = f;
    unsigned r = v.u + 0x7fffu + ((v.u >> 16) & 1u);   // round-to-nearest-even
    return (short)(r >> 16);
}

// pack two f32 -> packed bf16 pair (round-half-up): 2 adds + 1 v_perm.
static __device__ __forceinline__ unsigned pack2bf(float lo, float hi) {
    union { float f; unsigned u; } a, b;
    a.f = lo; b.f = hi;
    return __builtin_amdgcn_perm(b.u + 0x8000u, a.u + 0x8000u, 0x07060302u);
}

// async global->LDS DMA, 16B/lane; LDS dest = wave-uniform base + lane*16.
static __device__ __forceinline__ void dma16(const short* g, short* l) {
    __builtin_amdgcn_global_load_lds((const __attribute__((address_space(1))) void*)g,
                                     (__attribute__((address_space(3))) void*)l, 16, 0, 0);
}

// ---------------- 1) fp32 -> bf16: x and the 4 weight matrices ----------------
__global__ __launch_bounds__(256) void convert_all(
    const float* __restrict__ x,  const float* __restrict__ wq,
    const float* __restrict__ wk, const float* __restrict__ wv,
    const float* __restrict__ wo, short* __restrict__ xb, short* __restrict__ wb) {
    int idx = blockIdx.x * 256 + threadIdx.x;
    for (int i = idx; i < 2097152; i += gridDim.x * 256) {
        const float* src; short* dst;
        if (i < 1048576) {
            src = x + (size_t)i * 4;
            dst = xb + (size_t)i * 4;
        } else {
            int j = i - 1048576;
            int sel = j >> 18;
            const float* w = (sel == 0) ? wq : (sel == 1) ? wk : (sel == 2) ? wv : wo;
            src = w + (size_t)(j & 262143) * 4;
            dst = wb + (size_t)j * 4;
        }
        float4v v = *(const float4v*)src;
        short4v o;
        o.x = f2bf(v.x); o.y = f2bf(v.y); o.z = f2bf(v.z); o.w = f2bf(v.w);
        *(short4v*)dst = o;
    }
}

// ---------------- 2+4) fill augmented dims of Q'/K' (gram inline) ----------------
__global__ __launch_bounds__(256) void fill_aug(const float* __restrict__ harm,
                                                short* __restrict__ Qp,
                                                short* __restrict__ Kp) {
    int b  = blockIdx.y;
    int lc = blockIdx.x;
    int tid = threadIdx.x;
    int ll = tid >> 3;
    int d8 = (tid & 7) * 8;
    int l  = lc * 32 + ll;

    __shared__ float hs[64][33];
    for (int i = tid; i < 2048; i += 256) hs[i >> 5][i & 31] = harm[(size_t)b * 2048 + i];
    __syncthreads();

    float src = (l + 0.5f) * 0.0625f - 0.5f;
    if (src < 0.f) src = 0.f;
    int r0 = (int)floorf(src); if (r0 > 63) r0 = 63;
    int r1 = r0 + 1;           if (r1 > 63) r1 = 63;
    float wy = src - (float)r0;

    float hr[32];
    #pragma unroll
    for (int k = 0; k < 32; k++) hr[k] = (1.f - wy) * hs[r0][k] + wy * hs[r1][k];

    short8 qa, ka;
    #pragma unroll
    for (int j = 0; j < 8; j++) {
        float g = 0.f;
        #pragma unroll
        for (int k = 0; k < 32; k++) g += hr[k] * hs[d8 + j][k];
        qa[j] = f2bf(0.1f * LOG2E * g);
    }
    #pragma unroll
    for (int j = 0; j < 8; j++) {
        float vv = 0.f;
        if (d8 + j == r0) vv += 1.f - wy;
        if (d8 + j == r1) vv += wy;
        ka[j] = f2bf(vv);
    }
    for (int h = 0; h < 16; h++) {
        size_t base = (((size_t)(b * 16 + h) * 1024 + l) << 7) + 64 + d8;
        *(short8*)(Qp + base) = qa;
        *(short8*)(Kp + base) = ka;
    }
}

// ---------------- 3/6) GEMM (R7 structure, unchanged) ----------------
template <int MODE>
__global__ __launch_bounds__(256, 2) void gemm_kernel(
    const short* __restrict__ A,
    const short* __restrict__ Wb,
    const float* __restrict__ B0, const float* __restrict__ B1, const float* __restrict__ B2,
    short* __restrict__ Qp, short* __restrict__ Kp, short* __restrict__ Vp,
    float* __restrict__ outF) {
    const int z = blockIdx.z;
    const short* W  = Wb + (size_t)z * 1048576;
    const float* Bs = (z == 0) ? B0 : ((z == 1) ? B1 : B2);

    __shared__ short Sm[2][8192];   // [buf][A 0..4096 | W 4096..8192], 32 KB

    const int tid  = threadIdx.x;
    const int lane = tid & 63;
    const int wv   = tid >> 6;
    const int wm   = (wv >> 1) * 64;
    const int wn   = (wv & 1) * 64;
    const int l16  = lane & 15;
    const int quad = lane >> 4;
    const int bm   = blockIdx.x * 128;
    const int bn   = blockIdx.y * 128;

    const short* aSrc[2];
    const short* wSrc[2];
    #pragma unroll
    for (int j = 0; j < 2; j++) {
        int c = j * 256 + tid;
        int r = c >> 2, gs = (c & 3) ^ ((r >> 1) & 3);
        aSrc[j] = A + (size_t)(bm + r) * 1024 + gs * 8;
        wSrc[j] = W + (size_t)(bn + r) * 1024 + gs * 8;
    }
    const int fr = (quad ^ ((l16 >> 1) & 3)) * 8;
    int ai[4], bi[4];
    #pragma unroll
    for (int t = 0; t < 4; t++) {
        ai[t] = (wm + t * 16 + l16) * 32 + fr;
        bi[t] = 4096 + (wn + t * 16 + l16) * 32 + fr;
    }

    float4v zero4 = {0.f, 0.f, 0.f, 0.f};
    float4v acc[4][4];
    #pragma unroll
    for (int i = 0; i < 4; i++)
        #pragma unroll
        for (int j = 0; j < 4; j++) acc[i][j] = zero4;

    dma16(aSrc[0], &Sm[0][wv * 512]);
    dma16(aSrc[1], &Sm[0][2048 + wv * 512]);
    dma16(wSrc[0], &Sm[0][4096 + wv * 512]);
    dma16(wSrc[1], &Sm[0][6144 + wv * 512]);
    #pragma unroll
    for (int j = 0; j < 2; j++) { aSrc[j] += 32; wSrc[j] += 32; }
    __syncthreads();

    for (int kt = 0; kt < 32; kt++) {
        const int cur = kt & 1, nxt = cur ^ 1;
        if (kt < 31) {
            dma16(aSrc[0], &Sm[nxt][wv * 512]);
            dma16(aSrc[1], &Sm[nxt][2048 + wv * 512]);
            dma16(wSrc[0], &Sm[nxt][4096 + wv * 512]);
            dma16(wSrc[1], &Sm[nxt][6144 + wv * 512]);
            #pragma unroll
            for (int j = 0; j < 2; j++) { aSrc[j] += 32; wSrc[j] += 32; }
        }

        short8 af[4], bfr[4];
        #pragma unroll
        for (int mt = 0; mt < 4; mt++) af[mt]  = *(const short8*)&Sm[cur][ai[mt]];
        #pragma unroll
        for (int nt = 0; nt < 4; nt++) bfr[nt] = *(const short8*)&Sm[cur][bi[nt]];
        #pragma unroll
        for (int mt = 0; mt < 4; mt++)
            #pragma unroll
            for (int nt = 0; nt < 4; nt++)
                acc[mt][nt] = MFMA16(af[mt], bfr[nt], acc[mt][nt]);

        __syncthreads();
    }

    #pragma unroll
    for (int mt = 0; mt < 4; mt++)
        #pragma unroll
        for (int nt = 0; nt < 4; nt++) {
            int col = bn + wn + nt * 16 + l16;
            float bias = Bs[col];
            #pragma unroll
            for (int r = 0; r < 4; r++) {
                int row = bm + wm + mt * 16 + quad * 4 + r;
                float val = acc[mt][nt][r] + bias;
                if (MODE == 1) {
                    outF[(size_t)row * 1024 + col] = val;
                } else {
                    int b = row >> 10, l = row & 1023;
                    int h = col >> 6,  d = col & 63;
                    size_t bhl = (size_t)(b * 16 + h) * 1024 + l;
                    if (z == 0)      Qp[(bhl << 7) + d] = f2bf(val * (0.125f * LOG2E));
                    else if (z == 1) Kp[(bhl << 7) + d] = f2bf(val);
                    else {
                        int slot = (l & ~31) | (((l >> 2) & 3) << 3) |
                                   (((l >> 4) & 1) << 2) | (l & 3);
                        Vp[(((size_t)(b * 16 + h) * 64 + d) << 10) + slot] = f2bf(val);
                    }
                }
            }
        }
}

// ---------------- 5) flash attention: 512 thr, 8 waves x 32 q (256 q/block) ----------------
// K-fragments reused across 2 n-tiles -> LDS read volume per q-row halved vs R8.
// grid (16 h, 4 qb, 4 b) = 256 blocks = 1 block/CU.
__global__ __attribute__((amdgpu_flat_work_group_size(512, 512),
                          amdgpu_waves_per_eu(2, 2)))
void flash_kernel(const short* __restrict__ Qp,
                  const short* __restrict__ Kp,
                  const short* __restrict__ Vp,
                  short* __restrict__ AO) {
    const int h  = blockIdx.x;
    const int qb = blockIdx.y;          // 0..3, 256 q each
    const int b  = blockIdx.z;
    const int tid  = threadIdx.x;
    const int lane = tid & 63;
    const int w    = tid >> 6;          // wave 0..7, owns 32 q rows
    const int l16  = lane & 15;
    const int quad = lane >> 4;
    const size_t bh = (size_t)(b * 16 + h);

    __shared__ short Ks[16384];   // 2 x 8192 shorts (64 key x 128 d)
    __shared__ short Vs[8192];    // 2 x 4096 shorts (64 d x 64 slot)

    // Q fragments (B-operand): lane l16 -> q row, k = quad*8 + j
    short8 qf[2][4];
    #pragma unroll
    for (int n = 0; n < 2; n++) {
        const short* Qb = Qp + ((bh * 1024 + qb * 256 + w * 32 + n * 16 + l16) << 7) + quad * 8;
        #pragma unroll
        for (int c = 0; c < 4; c++) qf[n][c] = *(const short8*)(Qb + c * 32);
    }

    // staging sources (source-side swizzle, lane-linear LDS); 8 waves: 2 K + 1 V each
    const short* kSrc[2];
    #pragma unroll
    for (int jj = 0; jj < 2; jj++) {
        int key = (w * 2 + jj) * 4 + quad;
        kSrc[jj] = Kp + (bh << 17) + key * 128 + ((l16 ^ (key & 15)) * 8);
    }
    const short* vSrc;
    {
        int d = w * 8 + (lane >> 3);
        vSrc = Vp + (bh << 16) + d * 1024 + (((lane & 7) ^ (d & 7)) * 8);
    }

    int krd[4];
    #pragma unroll
    for (int c = 0; c < 4; c++) krd[c] = l16 * 128 + (((c * 4 + quad) ^ l16) * 8);
    int vrd[2];
    #pragma unroll
    for (int g = 0; g < 2; g++) vrd[g] = l16 * 64 + (((g * 4 + quad) ^ (l16 & 7)) * 8);

    // prologue: tile 0 -> buf 0
    #pragma unroll
    for (int jj = 0; jj < 2; jj++) dma16(kSrc[jj], &Ks[w * 1024 + jj * 512]);
    dma16(vSrc, &Vs[w * 512]);
    #pragma unroll
    for (int jj = 0; jj < 2; jj++) kSrc[jj] += 8192;
    vSrc += 64;
    int dstK = 8192, dstV = 4096;

    float4v zero4 = {0.f, 0.f, 0.f, 0.f};
    float4v o_acc[4][2];
    #pragma unroll
    for (int mt = 0; mt < 4; mt++)
        #pragma unroll
        for (int n = 0; n < 2; n++) o_acc[mt][n] = zero4;
    float l_part[2] = {0.f, 0.f};

    __syncthreads();

    for (int kt = 0; kt < 16; kt++) {
        if (kt < 15) {
            #pragma unroll
            for (int jj = 0; jj < 2; jj++) dma16(kSrc[jj], &Ks[dstK + w * 1024 + jj * 512]);
            dma16(vSrc, &Vs[dstV + w * 512]);
            #pragma unroll
            for (int jj = 0; jj < 2; jj++) kSrc[jj] += 8192;
            vSrc += 64;
            dstK ^= 8192; dstV ^= 4096;
        }

        // S^T = K·Q^T; kf read ONCE per mt, reused for both n-tiles
        float4v s[4][2];
        #pragma unroll
        for (int mt = 0; mt < 4; mt++) {
            short8 kf[4];
            #pragma unroll
            for (int c = 0; c < 4; c++) kf[c] = *(const short8*)&Ks[krd[c] + mt * 2048];
            #pragma unroll
            for (int n = 0; n < 2; n++) {
                s[mt][n] = zero4;
                #pragma unroll
                for (int c = 0; c < 4; c++)
                    s[mt][n] = MFMA16(kf[c], qf[n][c], s[mt][n]);
            }
        }

        // p = exp2(s); per-lane partial l
        #pragma unroll
        for (int mt = 0; mt < 4; mt++)
            #pragma unroll
            for (int n = 0; n < 2; n++)
                #pragma unroll
                for (int r = 0; r < 4; r++) {
                    float p = __builtin_exp2f(s[mt][n][r]);
                    s[mt][n][r] = p;
                    l_part[n] += p;
                }

        // O^T += V^T · P^T; vf read once per (g,mt), reused for both n
        #pragma unroll
        for (int g = 0; g < 2; g++) {
            short8 pf[2];
            #pragma unroll
            for (int n = 0; n < 2; n++) {
                union { unsigned u[4]; short8 v; } t;
                t.u[0] = pack2bf(s[2 * g][n][0], s[2 * g][n][1]);
                t.u[1] = pack2bf(s[2 * g][n][2], s[2 * g][n][3]);
                t.u[2] = pack2bf(s[2 * g + 1][n][0], s[2 * g + 1][n][1]);
                t.u[3] = pack2bf(s[2 * g + 1][n][2], s[2 * g + 1][n][3]);
                pf[n] = t.v;
            }
            #pragma unroll
            for (int mt = 0; mt < 4; mt++) {
                short8 vf = *(const short8*)&Vs[vrd[g] + mt * 1024];
                #pragma unroll
                for (int n = 0; n < 2; n++)
                    o_acc[mt][n] = MFMA16(vf, pf[n], o_acc[mt][n]);
            }
        }

        if (kt < 15) __syncthreads();
        #pragma unroll
        for (int c = 0; c < 4; c++) krd[c] ^= 8192;
        #pragma unroll
        for (int g = 0; g < 2; g++) vrd[g] ^= 4096;
    }

    // epilogue: reduce l across quads, normalize, store
    #pragma unroll
    for (int n = 0; n < 2; n++) {
        float l = l_part[n];
        l += __shfl_xor(l, 16, 64);
        l += __shfl_xor(l, 32, 64);
        float inv = 1.0f / l;
        int row = b * 1024 + qb * 256 + w * 32 + n * 16 + l16;
        #pragma unroll
        for (int mt = 0; mt < 4; mt++) {
            short4v ov;
            #pragma unroll
            for (int r = 0; r < 4; r++) ov[r] = f2bf(o_acc[mt][n][r] * inv);
            *(short4v*)(AO + (size_t)row * 1024 + h * 64 + mt * 16 + quad * 4) = ov;
        }
    }
}

extern "C" void kernel_launch(void* const* d_in, const int* in_sizes, int n_in,
                              void* d_out, int out_size, void* d_ws, size_t ws_size,
                              hipStream_t stream) {
    const float* x    = (const float*)d_in[0];
    const float* harm = (const float*)d_in[1];
    const float* wq   = (const float*)d_in[2];
    const float* bq   = (const float*)d_in[3];
    const float* wk   = (const float*)d_in[4];
    const float* bk   = (const float*)d_in[5];
    const float* wv   = (const float*)d_in[6];
    const float* bv   = (const float*)d_in[7];
    const float* wo   = (const float*)d_in[8];
    const float* bo   = (const float*)d_in[9];
    float* outF = (float*)d_out;

    short* xb   = (short*)d_ws;                 // 4M shorts; ALIASED as AO
    short* Qp   = xb + (size_t)4 * 1048576;     // 8M shorts
    short* Kp   = Qp + (size_t)8 * 1048576;     // 8M shorts
    short* Vp   = Kp + (size_t)8 * 1048576;     // 4M shorts
    short* Wqkv = Vp + (size_t)4 * 1048576;     // 3M shorts (wq,wk,wv)
    short* Wob  = Wqkv + (size_t)3 * 1048576;   // 1M shorts (wo)
    short* AO   = xb;   // alias: xb consumed by QKV GEMM before flash writes AO

    convert_all<<<dim3(2048), dim3(256), 0, stream>>>(x, wq, wk, wv, wo, xb, Wqkv);
    gemm_kernel<0><<<dim3(32, 8, 3), dim3(256), 0, stream>>>(
        xb, Wqkv, bq, bk, bv, Qp, Kp, Vp, nullptr);
    fill_aug<<<dim3(32, 4), dim3(256), 0, stream>>>(harm, Qp, Kp);
    flash_kernel<<<dim3(16, 4, 4), dim3(512), 0, stream>>>(Qp, Kp, Vp, AO);
    gemm_kernel<1><<<dim3(32, 8, 1), dim3(256), 0, stream>>>(
        AO, Wob, bo, nullptr, nullptr, nullptr, nullptr, nullptr, outF);
}